// Round 4
// baseline (291.944 us; speedup 1.0000x reference)
//
#include <hip/hip_runtime.h>

typedef short bf16x8 __attribute__((ext_vector_type(8)));
typedef float f32x4 __attribute__((ext_vector_type(4)));

#define DI __device__ __forceinline__

#if __has_builtin(__builtin_amdgcn_exp2f)
#define EXP2(x) __builtin_amdgcn_exp2f(x)
#else
#define EXP2(x) exp2f(x)
#endif

// log2(e), 1/sqrt(32)*log2(e)
#define LOG2E 1.44269504088896f
#define QSCALE (0.17677669529663687f * 1.44269504088896f)

static DI unsigned short f2bf(float f) {
  union { float f; unsigned u; } v; v.f = f;
  unsigned r = v.u + 0x7FFFu + ((v.u >> 16) & 1u);  // RNE
  return (unsigned short)(r >> 16);
}

static DI unsigned cvt_pk_bf16(float lo, float hi) {
  unsigned r;
  asm("v_cvt_pk_bf16_f32 %0, %1, %2" : "=v"(r) : "v"(lo), "v"(hi));
  return r;
}

// ---------------------------------------------------------------------------
// Weight prep. Wt_qkvg: [N=1024][K=256] bf16 n-major. Wt_o: rows k-PERMUTED
// with pi(h*32+d) = h*32 + (d&15)*2 + (d>>4) to match attn_out's packed
// column layout (k-dim permutation applied to both GEMM operands = no-op).
// ---------------------------------------------------------------------------
__global__ __launch_bounds__(256) void k_cast_weights(
    const float* __restrict__ Wq, const float* __restrict__ Wk,
    const float* __restrict__ Wv, const float* __restrict__ Wg,
    const float* __restrict__ Wo,
    unsigned short* __restrict__ Wt_qkvg, unsigned short* __restrict__ Wt_o) {
  int t = blockIdx.x * 256 + threadIdx.x;
  if (t < 262144) {
    int n = t & 1023, kk = t >> 10;
    const float* W = (n < 256) ? Wq : (n < 512) ? Wk : (n < 768) ? Wv : Wg;
    Wt_qkvg[(size_t)n * 256 + kk] = f2bf(W[kk * 256 + (n & 255)]);
  } else if (t < 262144 + 65536) {
    int u = t - 262144;
    int n = u & 255, kk = u >> 8;
    int h = kk >> 5, e = kk & 31;
    int d = (e >> 1) + ((e & 1) << 4);  // pi^-1
    Wt_o[n * 256 + kk] = f2bf(Wo[(h * 32 + d) * 256 + n]);
  }
}

// ---------------------------------------------------------------------------
// rmsnorm(m) -> bf16. One wave per 256-elem row, float4 per lane.
// ---------------------------------------------------------------------------
__global__ __launch_bounds__(256) void k_rmsnorm_m(
    const float* __restrict__ m, const float* __restrict__ w,
    unsigned short* __restrict__ m_norm) {
  int wave = threadIdx.x >> 6, lane = threadIdx.x & 63;
  int row = blockIdx.x * 4 + wave;
  const float4 x = *(const float4*)(m + (size_t)row * 256 + lane * 4);
  float ss = x.x * x.x + x.y * x.y + x.z * x.z + x.w * x.w;
#pragma unroll
  for (int mk = 1; mk < 64; mk <<= 1) ss += __shfl_xor(ss, mk, 64);
  float rms = rsqrtf(ss * (1.0f / 256.0f) + 1e-5f);
  const float4 wv = *(const float4*)(w + lane * 4);
  ushort4 o;
  o.x = f2bf(x.x * rms * wv.x);
  o.y = f2bf(x.y * rms * wv.y);
  o.z = f2bf(x.z * rms * wv.z);
  o.w = f2bf(x.w * rms * wv.w);
  *(ushort4*)(m_norm + (size_t)row * 256 + lane * 4) = o;
}

// ---------------------------------------------------------------------------
// Pair bias -> swizzled MFMA C-fragment layout, pre-scaled by log2(e):
//   bidx(h,i,j) = h*262144 + (i>>4)*8192 + (j>>4)*256
//               + (((i>>2)&3)*16 + (j&15))*4 + (i&3)
// so k_attn lane l loads f32x4 at [h][i>>4][t][l*4] (fully coalesced) and
// feeds it as the C operand of the QK^T MFMA (C layout: col=l&15,
// row=(l>>4)*4+reg). Streaming structure unchanged from R2 (coalesced 1KB).
// ---------------------------------------------------------------------------
__global__ __launch_bounds__(256) void k_pair_bias(
    const float* __restrict__ z, const float* __restrict__ z_mask,
    const float* __restrict__ w_norm_z, const float* __restrict__ Wz,
    float* __restrict__ bias) {
  int gw = blockIdx.x * 4 + (threadIdx.x >> 6);   // global wave 0..16383
  int lane = threadIdx.x & 63;
  int half = lane >> 5, li = lane & 31;
  f32x4 wzl[4], wzh[4];
#pragma unroll
  for (int i = 0; i < 4; ++i) {
    wzl[i] = *(const f32x4*)(Wz + (li * 4 + i) * 8);
    wzh[i] = *(const f32x4*)(Wz + (li * 4 + i) * 8 + 4);
  }
  const float4 wn = *(const float4*)(w_norm_z + li * 4);

  for (int it = 0; it < 8; ++it) {
    int row = it * 32768 + gw * 2 + half;
    const float4 a = *(const float4*)(z + (size_t)row * 128 + li * 4);
    float mb = (z_mask[row] > 0.0f) ? 0.0f : -1e9f;

    float ss = a.x * a.x + a.y * a.y + a.z * a.z + a.w * a.w;
#pragma unroll
    for (int mk = 1; mk < 32; mk <<= 1) ss += __shfl_xor(ss, mk, 64);
    float rms = rsqrtf(ss * (1.0f / 128.0f) + 1e-5f);

    float y0 = a.x * wn.x, y1 = a.y * wn.y, y2 = a.z * wn.z, y3 = a.w * wn.w;
    f32x4 pl = y0 * wzl[0] + y1 * wzl[1] + y2 * wzl[2] + y3 * wzl[3];
    f32x4 ph = y0 * wzh[0] + y1 * wzh[1] + y2 * wzh[2] + y3 * wzh[3];

    int b0 = li & 1, b1 = (li >> 1) & 1, b2 = (li >> 2) & 1;
    float A[4] = {pl[0], pl[2], ph[0], ph[2]};
    float Bv[4] = {pl[1], pl[3], ph[1], ph[3]};
    float keep[4];
#pragma unroll
    for (int i = 0; i < 4; ++i) {
      float send = b0 ? A[i] : Bv[i];
      float recv = __shfl_xor(send, 1, 64);
      keep[i] = (b0 ? Bv[i] : A[i]) + recv;
    }
    float s2x = b1 ? keep[0] : keep[1];
    float s2y = b1 ? keep[2] : keep[3];
    float r2x = __shfl_xor(s2x, 2, 64);
    float r2y = __shfl_xor(s2y, 2, 64);
    float k2x = (b1 ? keep[1] : keep[0]) + r2x;
    float k2y = (b1 ? keep[3] : keep[2]) + r2y;
    float s3 = b2 ? k2x : k2y;
    float r3 = __shfl_xor(s3, 4, 64);
    float fin = (b2 ? k2y : k2x) + r3;
    fin += __shfl_xor(fin, 8, 64);
    fin += __shfl_xor(fin, 16, 64);

    if (li < 8) {
      int i = row >> 9, j = row & 511;
      size_t bidx = (size_t)li * 262144 + (i >> 4) * 8192 + (j >> 4) * 256 +
                    (((i >> 2) & 3) * 16 + (j & 15)) * 4 + (i & 3);
      bias[bidx] = (fin * rms + mb) * LOG2E;
    }
  }
}

// ---------------------------------------------------------------------------
// Shared 128x128 MFMA GEMM mainloop (unchanged from R2).
// ---------------------------------------------------------------------------
DI void gemm_mainloop(const unsigned short* __restrict__ Amat,
                      const unsigned short* __restrict__ Btmat,
                      int mb, int nb, f32x4 acc[4][4],
                      unsigned short* At, unsigned short* Bts) {
  int tid = threadIdx.x, lane = tid & 63;
  int wm = (tid >> 6) >> 1, wn = (tid >> 6) & 1;
  int r16 = lane & 15, g8 = (lane >> 4) * 8;
  for (int kb = 0; kb < 256; kb += 32) {
#pragma unroll
    for (int u = 0; u < 2; ++u) {
      int c = u * 256 + tid;
      int rrow = c >> 2, gg = (c & 3) * 8;
      *(bf16x8*)(At + rrow * 40 + gg) =
          *(const bf16x8*)(Amat + (size_t)(mb + rrow) * 256 + kb + gg);
      *(bf16x8*)(Bts + rrow * 40 + gg) =
          *(const bf16x8*)(Btmat + (size_t)(nb + rrow) * 256 + kb + gg);
    }
    __syncthreads();
    bf16x8 af[4], bfr[4];
#pragma unroll
    for (int i = 0; i < 4; ++i)
      af[i] = *(const bf16x8*)(At + (wm * 64 + i * 16 + r16) * 40 + g8);
#pragma unroll
    for (int j = 0; j < 4; ++j)
      bfr[j] = *(const bf16x8*)(Bts + (wn * 64 + j * 16 + r16) * 40 + g8);
#pragma unroll
    for (int i = 0; i < 4; ++i)
#pragma unroll
      for (int j = 0; j < 4; ++j)
        acc[i][j] = __builtin_amdgcn_mfma_f32_16x16x32_bf16(af[i], bfr[j],
                                                            acc[i][j], 0, 0, 0);
    __syncthreads();
  }
}

// GEMM 1: m_norm @ [Wq|Wk|Wv|Wg]. q pre-scaled by 1/sqrt(D)*log2(e).
__global__ __launch_bounds__(256) void k_gemm_qkvg(
    const unsigned short* __restrict__ m_norm, const unsigned short* __restrict__ Wt,
    const float* __restrict__ bg,
    unsigned short* __restrict__ q_ws, unsigned short* __restrict__ k_ws,
    unsigned short* __restrict__ v_ws, float* __restrict__ g_ws) {
  __shared__ unsigned short At[128 * 40];
  __shared__ unsigned short Bts[128 * 40];
  int mb = blockIdx.x * 128, nb = blockIdx.y * 128;
  f32x4 acc[4][4] = {};
  gemm_mainloop(m_norm, Wt, mb, nb, acc, At, Bts);
  int lane = threadIdx.x & 63;
  int wm = (threadIdx.x >> 6) >> 1, wn = (threadIdx.x >> 6) & 1;
  int r16 = lane & 15, rg = lane >> 4;
#pragma unroll
  for (int i = 0; i < 4; ++i)
#pragma unroll
    for (int j = 0; j < 4; ++j) {
      int n = nb + wn * 64 + j * 16 + r16;
#pragma unroll
      for (int r = 0; r < 4; ++r) {
        int mrow = mb + wm * 64 + i * 16 + rg * 4 + r;
        int bb = mrow >> 9, s = mrow & 511;
        float v = acc[i][j][r];
        if (n < 768) {
          int tsel = n >> 8, hh = (n >> 5) & 7, dd = n & 31;
          unsigned short* dst = (tsel == 0) ? q_ws : (tsel == 1) ? k_ws : v_ws;
          float vv = (tsel == 0) ? v * QSCALE : v;
          dst[(((size_t)bb * 8 + hh) * 512 + s) * 32 + dd] = f2bf(vv);
        } else {
          int n2 = n & 255;
          g_ws[(size_t)mrow * 256 + n2] = v + bg[n2];
        }
      }
    }
}

// GEMM 2: attn_out @ Wt_o (both k-permuted), epilogue (+bo)*g -> fp32 out.
__global__ __launch_bounds__(256) void k_gemm_out(
    const unsigned short* __restrict__ attn_out, const unsigned short* __restrict__ Wt_o,
    const float* __restrict__ bo, const float* __restrict__ g_ws,
    float* __restrict__ out) {
  __shared__ unsigned short At[128 * 40];
  __shared__ unsigned short Bts[128 * 40];
  int mb = blockIdx.x * 128, nb = blockIdx.y * 128;
  f32x4 acc[4][4] = {};
  gemm_mainloop(attn_out, Wt_o, mb, nb, acc, At, Bts);
  int lane = threadIdx.x & 63;
  int wm = (threadIdx.x >> 6) >> 1, wn = (threadIdx.x >> 6) & 1;
  int r16 = lane & 15, rg = lane >> 4;
#pragma unroll
  for (int i = 0; i < 4; ++i)
#pragma unroll
    for (int j = 0; j < 4; ++j) {
      int n = nb + wn * 64 + j * 16 + r16;
#pragma unroll
      for (int r = 0; r < 4; ++r) {
        int mrow = mb + wm * 64 + i * 16 + rg * 4 + r;
        out[(size_t)mrow * 256 + n] = (acc[i][j][r] + bo[n]) * g_ws[(size_t)mrow * 256 + n];
      }
    }
}

// ---------------------------------------------------------------------------
// Attention. Per (b,h) block, 4 waves x 8 q-tiles. Changes vs R2:
//  - bias = MFMA C operand, loaded as coalesced f32x4 from swizzled layout
//  - exp2 (scales pre-folded), P unnormalized, 1/sum applied at output
//  - V/P LDS slot permutation (slot=2*(s&15)+((s>>4)&1) per 32-chunk) with
//    XOR bank swizzle (slot ^ ((d>>3)<<4)): staging writes 8-way -> 2-way
//  - P packed u32 via v_cvt_pk_bf16_f32, one ds_write_b32 per (c,r)
//  - output packed u32: columns pi-permuted (matched by Wt_o rows)
// ---------------------------------------------------------------------------
#define VT_LD 520
#define P_LD 40
__global__ __launch_bounds__(256, 2) void k_attn(
    const unsigned short* __restrict__ q_ws, const unsigned short* __restrict__ k_ws,
    const unsigned short* __restrict__ v_ws, const float* __restrict__ bias,
    unsigned short* __restrict__ attn_out) {
  __shared__ unsigned short Vt[32 * VT_LD];        // V^T slot-permuted (33,280 B)
  __shared__ unsigned short P_lds[4][16 * P_LD];   // per-wave P chunk (5,120 B)
  int tid = threadIdx.x;
  int wave = tid >> 6, lane = tid & 63;
  int bh = blockIdx.x;
  int h = bh >> 6, b = bh & 63;                    // h-major for L2 sharing
  size_t base = ((size_t)b * 8 + h) * (512 * 32);
  const unsigned short* qb = q_ws + base;
  const unsigned short* kb = k_ws + base;
  const unsigned short* vb = v_ws + base;
  // stage V: read [s][d] coalesced; scatter to slot-permuted, XOR-swizzled Vt
#pragma unroll
  for (int it = 0; it < 8; ++it) {
    int idx = it * 256 + tid;
    int s = idx >> 2, kk = idx & 3, d0 = kk * 8;
    bf16x8 vv = *(const bf16x8*)(vb + s * 32 + d0);
    int slot = (s & ~31) | ((s & 15) << 1) | ((s >> 4) & 1);
    int sx = slot ^ (kk << 4);
#pragma unroll
    for (int j = 0; j < 8; ++j) Vt[(d0 + j) * VT_LD + sx] = (unsigned short)vv[j];
  }
  __syncthreads();

  int r16 = lane & 15, g = lane >> 4;
  const float* biasp = bias + (size_t)h * 262144 + lane * 4;
  unsigned short* Pl = &P_lds[wave][0];
  unsigned short* ob = attn_out + ((size_t)b * 512) * 256 + h * 32;

  for (int qt = 0; qt < 8; ++qt) {
    int qbase = (wave * 8 + qt) * 16;
    const float* bq = biasp + qbase * 512;         // (qbase>>4)*8192
    bf16x8 qf = *(const bf16x8*)(qb + (qbase + r16) * 32 + g * 8);
    f32x4 sc[32];
#pragma unroll
    for (int t = 0; t < 32; ++t) {
      f32x4 cf = *(const f32x4*)(bq + t * 256);    // coalesced C-frag
      bf16x8 kf = *(const bf16x8*)(kb + (t * 16 + r16) * 32 + g * 8);
      sc[t] = __builtin_amdgcn_mfma_f32_16x16x32_bf16(qf, kf, cf, 0, 0, 0);
    }
    // row max (rows lane-group local: 4 shfl steps), exp2, sum
    float mx[4] = {-3e38f, -3e38f, -3e38f, -3e38f};
#pragma unroll
    for (int t = 0; t < 32; ++t)
#pragma unroll
      for (int r = 0; r < 4; ++r) mx[r] = fmaxf(mx[r], sc[t][r]);
#pragma unroll
    for (int r = 0; r < 4; ++r)
#pragma unroll
      for (int mk = 1; mk < 16; mk <<= 1)
        mx[r] = fmaxf(mx[r], __shfl_xor(mx[r], mk, 64));
    float sm[4] = {0.f, 0.f, 0.f, 0.f};
#pragma unroll
    for (int t = 0; t < 32; ++t)
#pragma unroll
      for (int r = 0; r < 4; ++r) {
        float e = EXP2(sc[t][r] - mx[r]);
        sc[t][r] = e;
        sm[r] += e;
      }
#pragma unroll
    for (int r = 0; r < 4; ++r)
#pragma unroll
      for (int mk = 1; mk < 16; mk <<= 1) sm[r] += __shfl_xor(sm[r], mk, 64);
    float inv[4];
#pragma unroll
    for (int r = 0; r < 4; ++r) inv[r] = 1.0f / sm[r];

    // PV with unnormalized P; per 32-chunk: pack 2 bf16 per u32 write.
    // P slot layout matches Vt slots: slot = 2*r16 + halfi.
    const f32x4 zero = {0.f, 0.f, 0.f, 0.f};
    f32x4 o0 = zero, o1 = zero;
    int rvx0 = (r16 >> 3) << 4;                    // vf0 XOR
    int rvx1 = ((r16 >> 3) + 2) << 4;              // vf1 XOR (d=r16+16)
#pragma unroll
    for (int c = 0; c < 16; ++c) {
#pragma unroll
      for (int r = 0; r < 4; ++r) {
        unsigned pk = cvt_pk_bf16(sc[c * 2][r], sc[c * 2 + 1][r]);
        *(unsigned*)(Pl + (g * 4 + r) * P_LD + r16 * 2) = pk;
      }
      bf16x8 pf = *(const bf16x8*)(Pl + r16 * P_LD + g * 8);
      bf16x8 vf0 = *(const bf16x8*)(Vt + r16 * VT_LD + ((c * 32 + g * 8) ^ rvx0));
      bf16x8 vf1 = *(const bf16x8*)(Vt + (r16 + 16) * VT_LD + ((c * 32 + g * 8) ^ rvx1));
      o0 = __builtin_amdgcn_mfma_f32_16x16x32_bf16(pf, vf0, o0, 0, 0, 0);
      o1 = __builtin_amdgcn_mfma_f32_16x16x32_bf16(pf, vf1, o1, 0, 0, 0);
    }
#pragma unroll
    for (int r = 0; r < 4; ++r) {
      int s = qbase + g * 4 + r;
      unsigned pk = cvt_pk_bf16(o0[r] * inv[r], o1[r] * inv[r]);
      *(unsigned*)(ob + (size_t)s * 256 + r16 * 2) = pk;  // pi-packed 64B runs
    }
  }
}

// ---------------------------------------------------------------------------
extern "C" void kernel_launch(void* const* d_in, const int* in_sizes, int n_in,
                              void* d_out, int out_size, void* d_ws, size_t ws_size,
                              hipStream_t stream) {
  (void)in_sizes; (void)n_in; (void)out_size; (void)ws_size;
  const float* m        = (const float*)d_in[0];
  const float* z        = (const float*)d_in[1];
  const float* z_mask   = (const float*)d_in[2];
  const float* w_norm_m = (const float*)d_in[3];
  const float* w_norm_z = (const float*)d_in[4];
  const float* Wq = (const float*)d_in[5];
  const float* Wk = (const float*)d_in[6];
  const float* Wv = (const float*)d_in[7];
  const float* Wz = (const float*)d_in[8];
  const float* Wg = (const float*)d_in[9];
  const float* bg = (const float*)d_in[10];
  const float* Wo = (const float*)d_in[11];
  const float* bo = (const float*)d_in[12];
  float* out = (float*)d_out;

  char* ws = (char*)d_ws;
  size_t off = 0;
  unsigned short* m_norm  = (unsigned short*)(ws + off); off += (size_t)32768 * 256 * 2;
  unsigned short* Wt_qkvg = (unsigned short*)(ws + off); off += (size_t)1024 * 256 * 2;
  unsigned short* Wt_o    = (unsigned short*)(ws + off); off += (size_t)256 * 256 * 2;
  unsigned short* q_ws    = (unsigned short*)(ws + off); off += (size_t)64 * 8 * 512 * 32 * 2;
  unsigned short* k_ws    = (unsigned short*)(ws + off); off += (size_t)64 * 8 * 512 * 32 * 2;
  unsigned short* v_ws    = (unsigned short*)(ws + off); off += (size_t)64 * 8 * 512 * 32 * 2;
  float* g_ws             = (float*)(ws + off);          off += (size_t)32768 * 256 * 4;
  float* bias             = (float*)(ws + off);          off += (size_t)8 * 512 * 512 * 4;
  unsigned short* attn_out = m_norm;  // m_norm dead after k_gemm_qkvg

  hipLaunchKernelGGL(k_cast_weights, dim3(1280), dim3(256), 0, stream,
                     Wq, Wk, Wv, Wg, Wo, Wt_qkvg, Wt_o);
  hipLaunchKernelGGL(k_rmsnorm_m, dim3(8192), dim3(256), 0, stream, m, w_norm_m, m_norm);
  hipLaunchKernelGGL(k_pair_bias, dim3(4096), dim3(256), 0, stream,
                     z, z_mask, w_norm_z, Wz, bias);
  hipLaunchKernelGGL(k_gemm_qkvg, dim3(256, 8), dim3(256), 0, stream,
                     m_norm, Wt_qkvg, bg, q_ws, k_ws, v_ws, g_ws);
  hipLaunchKernelGGL(k_attn, dim3(512), dim3(256), 0, stream,
                     q_ws, k_ws, v_ws, bias, attn_out);
  hipLaunchKernelGGL(k_gemm_out, dim3(256, 2), dim3(256), 0, stream,
                     attn_out, Wt_o, bo, g_ws, out);
}